// Round 2
// baseline (249.381 us; speedup 1.0000x reference)
//
#include <hip/hip_runtime.h>
#include <hip/hip_cooperative_groups.h>

namespace cg = cooperative_groups;

// B=4, M=8, N=128, D=32, K=2D=H=64
#define BMC 32
#define NNC 128
#define DDC 32
#define KKC 64
constexpr int ND = NNC * DDC;   // 4096
constexpr int NK = NNC * KKC;   // 8192
#define SMALLV 1e-8f

__device__ __forceinline__ float gelu_f(float v) {
    // tanh-gelu folded: gelu(v) = v - v * rcp(1 + exp2(v*(a*v^2+b)))
    float v2 = v * v;
    float p  = fmaf(0.1029432f, v2, 2.3022082f);
    float e  = __builtin_amdgcn_exp2f(v * p);
    float r  = __builtin_amdgcn_rcpf(e + 1.0f);
    return fmaf(-v, r, v);
}

// ===========================================================================
// Fused cooperative kernel. Grid = 512 x 256 (2 blocks/CU guaranteed:
// LDS 30 KB -> 2/CU even under a 64 KB runtime budget; launch_bounds(256,2)).
//   Phase 1 (all 512 blocks):  stats + MLP1 + A1/A2   (bm = blk>>4, nt = blk&15)
//   Phase 2 (2 tiles/block):   pair interactions      (tile = blk, blk+512)
//   Phase 3 (256 outs/block):  partial-sum + residual + mask
// ===========================================================================
__global__ __launch_bounds__(256, 2) void fused_kernel(
    const float* __restrict__ x, const float* __restrict__ x_size,
    const float* __restrict__ W1a, const float* __restrict__ b1a,
    const float* __restrict__ W1b, const float* __restrict__ b1b,
    const float* __restrict__ W2a, const float* __restrict__ b2a,
    const float* __restrict__ W2b, const float* __restrict__ b2b,
    const float* __restrict__ w3, const float* __restrict__ b3,
    float* __restrict__ x1g, float* __restrict__ A1g, float* __restrict__ A2t,
    float* __restrict__ v2g, float* __restrict__ c3g,
    float* __restrict__ partial, float* __restrict__ out)
{
    __shared__ __align__(16) float smem[7680];   // 30 KB arena, overlaid per phase

    const int t   = threadIdx.x;
    const int blk = blockIdx.x;
    cg::grid_group grid = cg::this_grid();

    // ======================= Phase 1: MLP / stats =======================
    {
        float* sW1a = smem;            // 2048 floats
        float* sW1b = smem + 2048;     // 2048
        float* sW2a = smem + 4096;     // 2048
        float* sXn  = smem + 6144;     // 256
        float* sH   = smem + 6400;     // 512
        float* sX1  = smem + 6912;     // 256
        float* sB1a = smem + 7168;     // 64
        float* sB2a = smem + 7232;     // 64
        float* sB1b = smem + 7296;     // 32
        float* sAny = smem + 7328;     // 128
        float* sRed = smem + 7456;     // 4

        const int bm = blk >> 4;
        const int nt = blk & 15;
        const int n0 = nt * 8;
        const int w  = t >> 6;

        // Stage weights (512 float4 per matrix, 2 per thread)
        {
            const float4* a4 = (const float4*)W1a;
            const float4* b4 = (const float4*)W1b;
            const float4* c4 = (const float4*)W2a;
            float4* sa = (float4*)sW1a; float4* sb = (float4*)sW1b; float4* sc = (float4*)sW2a;
            sa[t] = a4[t]; sa[t + 256] = a4[t + 256];
            sb[t] = b4[t]; sb[t + 256] = b4[t + 256];
            sc[t] = c4[t]; sc[t + 256] = c4[t + 256];
        }
        if (t < KKC) { sB1a[t] = b1a[t]; sB2a[t] = b2a[t]; }
        if (t < DDC) { sB1b[t] = b1b[t]; }
        if (t < NNC) sAny[t] = 0.f;
        __syncthreads();

        // ---- per-(b,m) stats (redundant per block) ----
        const float4* xs4 = (const float4*)(x + (size_t)bm * ND);
        float4 v4[4];
        float lsum = 0.f;
        #pragma unroll
        for (int s = 0; s < 4; ++s) {
            int f = t + s * 256;
            float4 q = xs4[f];
            v4[s] = q;
            lsum += q.x + q.y + q.z + q.w;
            if (q.x != 0.f || q.y != 0.f || q.z != 0.f || q.w != 0.f) sAny[f >> 3] = 1.f;
        }
        #pragma unroll
        for (int off = 32; off; off >>= 1) lsum += __shfl_xor(lsum, off);
        if ((t & 63) == 0) sRed[w] = lsum;
        __syncthreads();
        const float denom = x_size[bm >> 3] * (float)DDC;
        const float mean  = (sRed[0] + sRed[1] + sRed[2] + sRed[3]) / denom;

        float lsq = 0.f;
        #pragma unroll
        for (int s = 0; s < 4; ++s) {
            int f = t + s * 256;
            float mk = sAny[f >> 3];
            float dx = v4[s].x - mean, dy = v4[s].y - mean;
            float dz = v4[s].z - mean, dw = v4[s].w - mean;
            lsq += mk * (dx * dx + dy * dy + dz * dz + dw * dw);
        }
        #pragma unroll
        for (int off = 32; off; off >>= 1) lsq += __shfl_xor(lsq, off);
        __syncthreads();
        if ((t & 63) == 0) sRed[w] = lsq;
        __syncthreads();
        const float sq  = sRed[0] + sRed[1] + sRed[2] + sRed[3];
        const float inv = 1.f / (sqrtf(sq / denom) + SMALLV);

        // ---- normalize own 8-row tile ----
        {
            float xv = x[(size_t)bm * ND + n0 * DDC + t];
            sXn[t] = (xv - mean) * inv * sAny[n0 + (t >> 5)];
        }
        __syncthreads();

        const int k = t & 63;

        // H = gelu(xn @ W1a + b1a): rows w, w+4
        #pragma unroll
        for (int r = 0; r < 2; ++r) {
            int n = w + r * 4;
            const float* xr = &sXn[n * DDC];
            float acc = sB1a[k];
            #pragma unroll
            for (int d = 0; d < DDC; ++d) acc = fmaf(xr[d], sW1a[d * KKC + k], acc);
            sH[n * KKC + k] = gelu_f(acc);
        }
        __syncthreads();

        // x1 = (H @ W1b + b1b) * mask
        {
            const int d2 = t & 31;
            const int n  = t >> 5;
            const float* hr = &sH[n * KKC];
            float acc = sB1b[d2];
            #pragma unroll
            for (int q = 0; q < KKC; ++q) acc = fmaf(hr[q], sW1b[q * DDC + d2], acc);
            float val = acc * sAny[n0 + n];
            sX1[n * DDC + d2] = val;
            x1g[(size_t)bm * ND + (n0 + n) * DDC + d2] = val;
        }
        __syncthreads();

        // A1 = x1@W2a + b2a ; A2 = xn@W2a (transposed store [k][j])
        #pragma unroll
        for (int r = 0; r < 2; ++r) {
            int n = w + r * 4;
            const float* x1r = &sX1[n * DDC];
            const float* xnr = &sXn[n * DDC];
            float a1 = sB2a[k], a2 = 0.f;
            #pragma unroll
            for (int d = 0; d < DDC; ++d) {
                a1 = fmaf(x1r[d], sW2a[d * KKC + k], a1);
                a2 = fmaf(xnr[d], sW2a[d * KKC + k], a2);
            }
            A1g[(size_t)bm * NK + (n0 + n) * KKC + k] = a1;
            A2t[(size_t)bm * NK + k * NNC + (n0 + n)] = a2;
        }

        if (blk == 0) {
            // v2[k] = sum_h W2b[k][h]*w3[h], parallel over 256 threads
            int kk = t >> 2, hq = t & 3;
            float p = 0.f;
            #pragma unroll
            for (int h = 0; h < 16; ++h)
                p = fmaf(W2b[kk * KKC + hq * 16 + h], w3[hq * 16 + h], p);
            __syncthreads();           // sH free for reuse
            sH[t] = p;
            __syncthreads();
            if (hq == 0) v2g[kk] = sH[t] + sH[t + 1] + sH[t + 2] + sH[t + 3];
            if (t < 64) {
                float q = b2b[t] * w3[t];
                #pragma unroll
                for (int off = 32; off; off >>= 1) q += __shfl_xor(q, off);
                if (t == 0) c3g[0] = q;
            }
        }
    }

    grid.sync();

    // ======================= Phase 2: pair interactions =======================
    // 2 tiles per block: tile = blk, blk + 512.
    {
        float* sA2 = smem;            // 4096 floats [k][j] 16 KB
        float* sA1 = smem + 4096;     // 512
        float* sX1 = smem + 4608;     // 256
        float* sS  = smem + 4864;     // 512
        float* sV2 = smem + 5376;     // 64

        #pragma unroll
        for (int rep = 0; rep < 2; ++rep) {
            const int tile = blk + rep * 512;
            const int bm = tile >> 5;
            const int jg = (tile >> 4) & 1;
            const int ig = tile & 15;

            const int iN = (int)(x_size[bm >> 3] + 0.5f);
            const bool active = (ig * 8 < iN) && (jg * 64 < iN);

            if (active) {
                const int wv   = t >> 6;
                const int lane = t & 63;

                // ---- stage A2 tile [k][j-local] (coalesced 256B rows) ----
                {
                    const float* A2b = A2t + (size_t)bm * NK + jg * 64;
                    float4* s4 = (float4*)sA2;
                    #pragma unroll
                    for (int s = 0; s < 4; ++s) {
                        int idx = t + s * 256;          // float4 index
                        int kk = idx >> 4, f = idx & 15;
                        s4[idx] = *(const float4*)(A2b + kk * NNC + f * 4);
                    }
                }
                // A1 rows (512 consecutive floats), x1 rows (256), v2
                {
                    const float2* a1s = (const float2*)(A1g + (size_t)bm * NK + ig * 8 * KKC);
                    ((float2*)sA1)[t] = a1s[t];
                    sX1[t] = x1g[(size_t)bm * ND + ig * 8 * DDC + t];
                    if (t < KKC) sV2[t] = v2g[t];
                }
                const float c3 = c3g[0];
                __syncthreads();

                // ---- wave wv handles i-chains 2*wv, 2*wv+1 ----
                {
                    const int i0 = wv * 2, i1 = i0 + 1;
                    float S0 = c3, S1 = c3;
                    #pragma unroll 8
                    for (int k = 0; k < KKC; ++k) {
                        float a2v = sA2[k * 64 + lane];
                        float vk  = sV2[k];
                        float a10 = sA1[i0 * KKC + k];
                        float a11 = sA1[i1 * KKC + k];
                        S0 = fmaf(gelu_f(a10 - a2v), vk, S0);
                        S1 = fmaf(gelu_f(a11 - a2v), vk, S1);
                    }
                    sS[i0 * 64 + lane] = S0;
                    sS[i1 * 64 + lane] = S1;
                }
                __syncthreads();

                // ---- rank-1 update: thread = (j = t>>2, dq = t&3), 8 d's each ----
                {
                    const int j  = t >> 2;
                    const int dq = t & 3;
                    float acc[8];
                    #pragma unroll
                    for (int d = 0; d < 8; ++d) acc[d] = 0.f;
                    #pragma unroll
                    for (int i = 0; i < 8; ++i) {
                        float Sv = sS[i * 64 + j];
                        const float4* xf = (const float4*)&sX1[i * DDC + dq * 8];
                        float4 xa = xf[0], xb = xf[1];
                        acc[0] = fmaf(Sv, xa.x, acc[0]);
                        acc[1] = fmaf(Sv, xa.y, acc[1]);
                        acc[2] = fmaf(Sv, xa.z, acc[2]);
                        acc[3] = fmaf(Sv, xa.w, acc[3]);
                        acc[4] = fmaf(Sv, xb.x, acc[4]);
                        acc[5] = fmaf(Sv, xb.y, acc[5]);
                        acc[6] = fmaf(Sv, xb.z, acc[6]);
                        acc[7] = fmaf(Sv, xb.w, acc[7]);
                    }
                    // partial layout: [bm][jg][ig][j-local][d]; thread-contiguous (t*8)
                    float* pb = partial + ((size_t)((bm * 2 + jg) * 16 + ig)) * 2048 + t * 8;
                    ((float4*)pb)[0] = make_float4(acc[0], acc[1], acc[2], acc[3]);
                    ((float4*)pb)[1] = make_float4(acc[4], acc[5], acc[6], acc[7]);
                }
            }
            // protect LDS overwrite before second rep's staging (block-uniform)
            if (rep == 0) __syncthreads();
        }
    }

    grid.sync();

    // ======================= Phase 3: finalize =======================
    // 512 blocks x 256 outputs each.
    {
        const int gid = blk * 256 + t;                 // < 131072
        const int bm  = gid >> 12;
        const int rem = gid & 4095;                    // j*32 + d
        float xv = x[gid];
        unsigned long long bal = __ballot(xv != 0.f);
        int lane = t & 63;
        unsigned long long half = (lane < 32) ? (bal & 0xFFFFFFFFull) : (bal >> 32);
        if (half == 0ull) { out[gid] = 0.f; return; }

        const int iN  = (int)(x_size[bm >> 3] + 0.5f);
        const int nig = (iN + 7) >> 3;                 // valid i-groups (8..16)
        const int jgp = rem >> 11;                     // j-group (0/1)
        const size_t pb = ((size_t)((bm * 2 + jgp) * 16)) * 2048 + (rem & 2047);
        float sum = 0.f;
        for (int ig = 0; ig < nig; ++ig) sum += partial[pb + (size_t)ig * 2048];
        out[gid] = sum + b3[0] + xv;
    }
}

// ===========================================================================
// Fallback path: the verified 3-kernel pipeline (round-0 code, 104 µs).
// Used only if the cooperative launch cannot co-schedule 512 blocks.
// ===========================================================================
__global__ __launch_bounds__(256) void mlp_kernel(
    const float* __restrict__ x, const float* __restrict__ x_size,
    const float* __restrict__ W1a, const float* __restrict__ b1a,
    const float* __restrict__ W1b, const float* __restrict__ b1b,
    const float* __restrict__ W2a, const float* __restrict__ b2a,
    const float* __restrict__ W2b, const float* __restrict__ b2b,
    const float* __restrict__ w3,
    float* __restrict__ x1g, float* __restrict__ A1g, float* __restrict__ A2t,
    float* __restrict__ v2g, float* __restrict__ c3g)
{
    __shared__ float sW1a[DDC * KKC];
    __shared__ float sW1b[KKC * DDC];
    __shared__ float sW2a[DDC * KKC];
    __shared__ float sXn[8 * DDC];
    __shared__ float sH[8 * KKC];
    __shared__ float sX1[8 * DDC];
    __shared__ float sB1a[KKC], sB2a[KKC], sB1b[DDC];
    __shared__ float sAny[NNC];
    __shared__ float sRed[4];

    const int t  = threadIdx.x;
    const int bm = blockIdx.x >> 4;
    const int nt = blockIdx.x & 15;
    const int n0 = nt * 8;
    const int w  = t >> 6;

    {
        const float4* a4 = (const float4*)W1a;
        const float4* b4 = (const float4*)W1b;
        const float4* c4 = (const float4*)W2a;
        float4* sa = (float4*)sW1a; float4* sb = (float4*)sW1b; float4* sc = (float4*)sW2a;
        sa[t] = a4[t]; sa[t + 256] = a4[t + 256];
        sb[t] = b4[t]; sb[t + 256] = b4[t + 256];
        sc[t] = c4[t]; sc[t + 256] = c4[t + 256];
    }
    if (t < KKC) { sB1a[t] = b1a[t]; sB2a[t] = b2a[t]; }
    if (t < DDC) { sB1b[t] = b1b[t]; }
    if (t < NNC) sAny[t] = 0.f;
    __syncthreads();

    const float4* xs4 = (const float4*)(x + (size_t)bm * ND);
    float4 v4[4];
    float lsum = 0.f;
    #pragma unroll
    for (int s = 0; s < 4; ++s) {
        int f = t + s * 256;
        float4 q = xs4[f];
        v4[s] = q;
        lsum += q.x + q.y + q.z + q.w;
        if (q.x != 0.f || q.y != 0.f || q.z != 0.f || q.w != 0.f) sAny[f >> 3] = 1.f;
    }
    #pragma unroll
    for (int off = 32; off; off >>= 1) lsum += __shfl_xor(lsum, off);
    if ((t & 63) == 0) sRed[w] = lsum;
    __syncthreads();
    const float denom = x_size[bm >> 3] * (float)DDC;
    const float mean  = (sRed[0] + sRed[1] + sRed[2] + sRed[3]) / denom;

    float lsq = 0.f;
    #pragma unroll
    for (int s = 0; s < 4; ++s) {
        int f = t + s * 256;
        float mk = sAny[f >> 3];
        float dx = v4[s].x - mean, dy = v4[s].y - mean;
        float dz = v4[s].z - mean, dw = v4[s].w - mean;
        lsq += mk * (dx * dx + dy * dy + dz * dz + dw * dw);
    }
    #pragma unroll
    for (int off = 32; off; off >>= 1) lsq += __shfl_xor(lsq, off);
    __syncthreads();
    if ((t & 63) == 0) sRed[w] = lsq;
    __syncthreads();
    const float sq  = sRed[0] + sRed[1] + sRed[2] + sRed[3];
    const float inv = 1.f / (sqrtf(sq / denom) + SMALLV);

    {
        float xv = x[(size_t)bm * ND + n0 * DDC + t];
        sXn[t] = (xv - mean) * inv * sAny[n0 + (t >> 5)];
    }
    __syncthreads();

    const int k = t & 63;

    #pragma unroll
    for (int r = 0; r < 2; ++r) {
        int n = w + r * 4;
        const float* xr = &sXn[n * DDC];
        float acc = sB1a[k];
        #pragma unroll
        for (int d = 0; d < DDC; ++d) acc = fmaf(xr[d], sW1a[d * KKC + k], acc);
        sH[n * KKC + k] = gelu_f(acc);
    }
    __syncthreads();

    {
        const int d2 = t & 31;
        const int n  = t >> 5;
        const float* hr = &sH[n * KKC];
        float acc = sB1b[d2];
        #pragma unroll
        for (int q = 0; q < KKC; ++q) acc = fmaf(hr[q], sW1b[q * DDC + d2], acc);
        float val = acc * sAny[n0 + n];
        sX1[n * DDC + d2] = val;
        x1g[(size_t)bm * ND + (n0 + n) * DDC + d2] = val;
    }
    __syncthreads();

    #pragma unroll
    for (int r = 0; r < 2; ++r) {
        int n = w + r * 4;
        const float* x1r = &sX1[n * DDC];
        const float* xnr = &sXn[n * DDC];
        float a1 = sB2a[k], a2 = 0.f;
        #pragma unroll
        for (int d = 0; d < DDC; ++d) {
            a1 = fmaf(x1r[d], sW2a[d * KKC + k], a1);
            a2 = fmaf(xnr[d], sW2a[d * KKC + k], a2);
        }
        A1g[(size_t)bm * NK + (n0 + n) * KKC + k] = a1;
        A2t[(size_t)bm * NK + k * NNC + (n0 + n)] = a2;
    }

    if (blockIdx.x == 0) {
        int kk = t >> 2, hq = t & 3;
        float p = 0.f;
        #pragma unroll
        for (int h = 0; h < 16; ++h)
            p = fmaf(W2b[kk * KKC + hq * 16 + h], w3[hq * 16 + h], p);
        __syncthreads();
        sH[t] = p;
        __syncthreads();
        if (hq == 0) v2g[kk] = sH[t] + sH[t + 1] + sH[t + 2] + sH[t + 3];
        if (t < 64) {
            float q = b2b[t] * w3[t];
            #pragma unroll
            for (int off = 32; off; off >>= 1) q += __shfl_xor(q, off);
            if (t == 0) c3g[0] = q;
        }
    }
}

__global__ __launch_bounds__(256) void pair_kernel(
    const float* __restrict__ x_size,
    const float* __restrict__ A1g, const float* __restrict__ A2t,
    const float* __restrict__ x1g, const float* __restrict__ v2g,
    const float* __restrict__ c3g, float* __restrict__ partial)
{
    __shared__ float sA2[KKC * 64];
    __shared__ float sA1[8 * KKC];
    __shared__ float sX1[8 * DDC];
    __shared__ float sS[8 * 64];
    __shared__ float sV2[KKC];

    const int t    = threadIdx.x;
    const int bm   = blockIdx.x >> 5;
    const int jg   = (blockIdx.x >> 4) & 1;
    const int ig   = blockIdx.x & 15;

    const int iN = (int)(x_size[bm >> 3] + 0.5f);
    if (ig * 8 >= iN || jg * 64 >= iN) return;

    const int wv   = t >> 6;
    const int lane = t & 63;

    {
        const float* A2b = A2t + (size_t)bm * NK + jg * 64;
        float4* s4 = (float4*)sA2;
        #pragma unroll
        for (int s = 0; s < 4; ++s) {
            int idx = t + s * 256;
            int k = idx >> 4, f = idx & 15;
            s4[idx] = *(const float4*)(A2b + k * NNC + f * 4);
        }
    }
    {
        const float2* a1s = (const float2*)(A1g + (size_t)bm * NK + ig * 8 * KKC);
        ((float2*)sA1)[t] = a1s[t];
        sX1[t] = x1g[(size_t)bm * ND + ig * 8 * DDC + t];
        if (t < KKC) sV2[t] = v2g[t];
    }
    const float c3 = c3g[0];
    __syncthreads();

    {
        const int i0 = wv * 2, i1 = i0 + 1;
        float S0 = c3, S1 = c3;
        #pragma unroll 8
        for (int k = 0; k < KKC; ++k) {
            float a2v = sA2[k * 64 + lane];
            float vk  = sV2[k];
            float a10 = sA1[i0 * KKC + k];
            float a11 = sA1[i1 * KKC + k];
            S0 = fmaf(gelu_f(a10 - a2v), vk, S0);
            S1 = fmaf(gelu_f(a11 - a2v), vk, S1);
        }
        sS[i0 * 64 + lane] = S0;
        sS[i1 * 64 + lane] = S1;
    }
    __syncthreads();

    {
        const int j  = t >> 2;
        const int dq = t & 3;
        float acc[8];
        #pragma unroll
        for (int d = 0; d < 8; ++d) acc[d] = 0.f;
        #pragma unroll
        for (int i = 0; i < 8; ++i) {
            float Sv = sS[i * 64 + j];
            const float4* xf = (const float4*)&sX1[i * DDC + dq * 8];
            float4 xa = xf[0], xb = xf[1];
            acc[0] = fmaf(Sv, xa.x, acc[0]);
            acc[1] = fmaf(Sv, xa.y, acc[1]);
            acc[2] = fmaf(Sv, xa.z, acc[2]);
            acc[3] = fmaf(Sv, xa.w, acc[3]);
            acc[4] = fmaf(Sv, xb.x, acc[4]);
            acc[5] = fmaf(Sv, xb.y, acc[5]);
            acc[6] = fmaf(Sv, xb.z, acc[6]);
            acc[7] = fmaf(Sv, xb.w, acc[7]);
        }
        float* pb = partial + ((size_t)((bm * 2 + jg) * 16 + ig)) * 2048 + t * 8;
        ((float4*)pb)[0] = make_float4(acc[0], acc[1], acc[2], acc[3]);
        ((float4*)pb)[1] = make_float4(acc[4], acc[5], acc[6], acc[7]);
    }
}

__global__ __launch_bounds__(256) void final_kernel(
    const float* __restrict__ x, const float* __restrict__ x_size,
    const float* __restrict__ b3,
    const float* __restrict__ partial, float* __restrict__ out)
{
    const int gid = blockIdx.x * 256 + threadIdx.x;
    const int bm  = gid >> 12;
    const int rem = gid & 4095;
    float xv = x[gid];
    unsigned long long bal = __ballot(xv != 0.f);
    int lane = threadIdx.x & 63;
    unsigned long long half = (lane < 32) ? (bal & 0xFFFFFFFFull) : (bal >> 32);
    if (half == 0ull) { out[gid] = 0.f; return; }

    const int iN  = (int)(x_size[bm >> 3] + 0.5f);
    const int nig = (iN + 7) >> 3;
    const int jgp = rem >> 11;
    const size_t pb = ((size_t)((bm * 2 + jgp) * 16)) * 2048 + (rem & 2047);
    float sum = 0.f;
    for (int ig = 0; ig < nig; ++ig) sum += partial[pb + (size_t)ig * 2048];
    out[gid] = sum + b3[0] + xv;
}

extern "C" void kernel_launch(void* const* d_in, const int* in_sizes, int n_in,
                              void* d_out, int out_size, void* d_ws, size_t ws_size,
                              hipStream_t stream) {
    const float* x      = (const float*)d_in[0];
    const float* x_size = (const float*)d_in[1];
    const float* W1a    = (const float*)d_in[2];
    const float* b1a    = (const float*)d_in[3];
    const float* W1b    = (const float*)d_in[4];
    const float* b1b    = (const float*)d_in[5];
    const float* W2a    = (const float*)d_in[6];
    const float* b2a    = (const float*)d_in[7];
    const float* W2b    = (const float*)d_in[8];
    const float* b2b    = (const float*)d_in[9];
    const float* w3     = (const float*)d_in[10];
    const float* b3     = (const float*)d_in[11];
    float* out = (float*)d_out;

    float* ws      = (float*)d_ws;
    float* x1g     = ws;                       // 131072
    float* A1g     = x1g + (size_t)BMC * ND;   // 262144
    float* A2t     = A1g + (size_t)BMC * NK;   // 262144
    float* v2g     = A2t + (size_t)BMC * NK;   // 64
    float* c3g     = v2g + KKC;                // 1 (+63 pad)
    float* partial = c3g + 64;                 // 1024*2048 = 2097152 (8 MB)

    // One-time capacity check for the cooperative path (host query, capture-legal).
    static int use_coop = -1;
    if (use_coop < 0) {
        int nb = 0;
        hipError_t e = hipOccupancyMaxActiveBlocksPerMultiprocessor(
            &nb, (const void*)fused_kernel, 256, 0);
        use_coop = (e == hipSuccess && nb >= 2) ? 1 : 0;   // need 512 blocks on 256 CUs
    }

    if (use_coop) {
        void* args[] = {
            (void*)&x, (void*)&x_size,
            (void*)&W1a, (void*)&b1a, (void*)&W1b, (void*)&b1b,
            (void*)&W2a, (void*)&b2a, (void*)&W2b, (void*)&b2b,
            (void*)&w3, (void*)&b3,
            (void*)&x1g, (void*)&A1g, (void*)&A2t, (void*)&v2g, (void*)&c3g,
            (void*)&partial, (void*)&out
        };
        hipError_t e = hipLaunchCooperativeKernel((const void*)fused_kernel,
                                                  dim3(512), dim3(256), args, 0, stream);
        if (e == hipSuccess) return;
        use_coop = 0;   // fall through to the proven pipeline
    }

    mlp_kernel<<<BMC * 16, 256, 0, stream>>>(x, x_size,
        W1a, b1a, W1b, b1b, W2a, b2a, W2b, b2b, w3,
        x1g, A1g, A2t, v2g, c3g);
    pair_kernel<<<BMC * 32, 256, 0, stream>>>(x_size, A1g, A2t, x1g, v2g, c3g, partial);
    final_kernel<<<512, 256, 0, stream>>>(x, x_size, b3, partial, out);
}

// Round 3
// 106.882 us; speedup vs baseline: 2.3332x; 2.3332x over previous
//
#include <hip/hip_runtime.h>

// B=4, M=8, N=128, D=32, K=2D=H=64
#define NNC 128
#define DDC 32
#define KKC 64
constexpr int ND = NNC * DDC;   // 4096 floats per (b,m)
#define SMALLV 1e-8f

__device__ __forceinline__ float gelu_f(float v) {
    // tanh-gelu folded: gelu(v) = v - v * rcp(1 + exp2(v*(a*v^2+b)))
    float v2 = v * v;
    float p  = fmaf(0.1029432f, v2, 2.3022082f);
    float e  = __builtin_amdgcn_exp2f(v * p);
    float r  = __builtin_amdgcn_rcpf(e + 1.0f);
    return fmaf(-v, r, v);
}

// ===========================================================================
// ONE ordinary kernel. Grid = 256 blocks = bm(32) x jt(8 tiles of 16 j).
// Each block redundantly computes its (b,m)'s MLP (stats + MLP1 + A1 + its
// A2 tile), then S[i][j] and the final aggregation, writing out directly.
// No grid sync, no workspace, no multi-kernel boundaries.
//
// LDS arena: exactly 16384 floats (64 KB), lifetime-overlaid:
//   [0,4096)      sX1  [128][32]                      (chunks -> end)
//   [4096,12416)  sA1  [128][65]  written late; overlays (all dead by then):
//                   sXn  [4096,8192)  [128][32]
//                   sH32 [8192,10240) [32][64]  (also v2-partial scratch early)
//   [12416,13568) sA2  [64][18]
//   [13568,15872) sS   [128][18]
//   [15872,...)   sV2[64], sAny[128], sRed[8], sC3[1]
// Weight matrices are register-cached as per-lane columns (no LDS, no
// ds-read-per-fma): colA=W1a[:,k], colB=W1b[:,d], colC=W2a[:,k].
// ===========================================================================
__global__ __launch_bounds__(256, 1) void fused2(
    const float* __restrict__ x, const float* __restrict__ x_size,
    const float* __restrict__ W1a, const float* __restrict__ b1a,
    const float* __restrict__ W1b, const float* __restrict__ b1b,
    const float* __restrict__ W2a, const float* __restrict__ b2a,
    const float* __restrict__ W2b, const float* __restrict__ b2b,
    const float* __restrict__ w3, const float* __restrict__ b3,
    float* __restrict__ out)
{
    __shared__ __align__(16) float smem[16384];

    const int t   = threadIdx.x;
    const int blk = blockIdx.x;
    const int bm  = blk >> 3;
    const int jt  = blk & 7;
    const int k   = t & 63;
    const int w   = t >> 6;
    const int dL  = t & 31;

    const int iN = (int)(x_size[bm >> 3] + 0.5f);

    float* sX1  = smem;
    float* sA1  = smem + 4096;
    float* sXn  = smem + 4096;     // overlay: dead before sA1 writes
    float* sH32 = smem + 8192;     // overlay: dead before sA1 writes
    float* scr  = smem + 8192;     // v2 partial scratch (early, same region)
    float* sA2  = smem + 12416;
    float* sS   = smem + 13568;
    float* sV2  = smem + 15872;
    float* sAny = smem + 15936;
    float* sRed = smem + 16064;
    float* sC3  = smem + 16072;

    // ---- fully-invalid j-tile: write zeros, done (block-uniform) ----
    if (jt * 16 >= iN) {
        ((float2*)(out + (size_t)bm * ND + jt * 512))[t] = make_float2(0.f, 0.f);
        return;
    }

    // ---- stage: register-cache weight columns; v2/c3 partials; init ----
    float colA[32];                       // W1a[:, k]
    #pragma unroll
    for (int d = 0; d < 32; ++d) colA[d] = W1a[d * 64 + k];
    float colB[64];                       // W1b[:, dL]
    #pragma unroll
    for (int q = 0; q < 64; ++q) colB[q] = W1b[q * 32 + dL];
    const float rb1a = b1a[k];
    const float rb1b = b1b[dL];
    const float rb2a = b2a[k];

    {   // v2 partials: v2[kk] = sum_h W2b[kk][h]*w3[h]
        const int kk = t >> 2, hq = t & 3;
        float p = 0.f;
        #pragma unroll
        for (int h = 0; h < 16; ++h)
            p = fmaf(W2b[kk * 64 + hq * 16 + h], w3[hq * 16 + h], p);
        scr[t] = p;
    }
    if (t < 64) {                         // c3 = sum_h b2b[h]*w3[h]
        float q = b2b[t] * w3[t];
        #pragma unroll
        for (int off = 32; off; off >>= 1) q += __shfl_xor(q, off);
        if (t == 0) sC3[0] = q;
    }
    if (t < 128) sAny[t] = 0.f;
    __syncthreads();                                   // A

    // ---- stats over x[bm] (x held in regs v4) ----
    const float4* xs4 = (const float4*)(x + (size_t)bm * ND);
    float4 v4[4];
    float lsum = 0.f;
    #pragma unroll
    for (int s = 0; s < 4; ++s) {
        int f = t + s * 256;
        float4 q = xs4[f];
        v4[s] = q;
        lsum += q.x + q.y + q.z + q.w;
        if (q.x != 0.f || q.y != 0.f || q.z != 0.f || q.w != 0.f) sAny[f >> 3] = 1.f;
    }
    #pragma unroll
    for (int off = 32; off; off >>= 1) lsum += __shfl_xor(lsum, off);
    if ((t & 63) == 0) sRed[w] = lsum;
    __syncthreads();                                   // B
    if ((t & 3) == 0)                                  // finalize v2
        sV2[t >> 2] = scr[t] + scr[t + 1] + scr[t + 2] + scr[t + 3];
    const float denom = x_size[bm >> 3] * 32.f;
    const float mean  = (sRed[0] + sRed[1] + sRed[2] + sRed[3]) / denom;
    float lsq = 0.f;
    #pragma unroll
    for (int s = 0; s < 4; ++s) {
        int f = t + s * 256;
        float mk = sAny[f >> 3];
        float dx = v4[s].x - mean, dy = v4[s].y - mean;
        float dz = v4[s].z - mean, dw = v4[s].w - mean;
        lsq += mk * (dx * dx + dy * dy + dz * dz + dw * dw);
    }
    #pragma unroll
    for (int off = 32; off; off >>= 1) lsq += __shfl_xor(lsq, off);
    __syncthreads();                                   // C (sRed reuse)
    if ((t & 63) == 0) sRed[w] = lsq;
    __syncthreads();                                   // D
    const float sq  = sRed[0] + sRed[1] + sRed[2] + sRed[3];
    const float inv = 1.f / (sqrtf(sq / denom) + SMALLV);

    // ---- normalize -> sXn ----
    #pragma unroll
    for (int s = 0; s < 4; ++s) {
        int f = t + s * 256;
        float mk = sAny[f >> 3] * inv;
        float4 q = v4[s];
        q.x = (q.x - mean) * mk; q.y = (q.y - mean) * mk;
        q.z = (q.z - mean) * mk; q.w = (q.w - mean) * mk;
        ((float4*)sXn)[f] = q;
    }
    __syncthreads();                                   // E

    // ---- MLP1 in 32-row chunks: H32 = gelu(xn@W1a+b1a); x1 = (H@W1b+b1b)*m ----
    for (int c = 0; c < 4; ++c) {
        const int rb = c * 32;
        const bool live = (rb < iN);
        if (live) {
            #pragma unroll
            for (int r = 0; r < 8; ++r) {
                const int nl = w + 4 * r;
                const float4* xr4 = (const float4*)&sXn[(rb + nl) * 32];
                float acc = rb1a;
                #pragma unroll
                for (int dq = 0; dq < 8; ++dq) {
                    float4 xv = xr4[dq];
                    acc = fmaf(xv.x, colA[4 * dq + 0], acc);
                    acc = fmaf(xv.y, colA[4 * dq + 1], acc);
                    acc = fmaf(xv.z, colA[4 * dq + 2], acc);
                    acc = fmaf(xv.w, colA[4 * dq + 3], acc);
                }
                sH32[nl * 64 + k] = gelu_f(acc);
            }
        }
        __syncthreads();                               // F_c
        if (live) {
            #pragma unroll
            for (int p = 0; p < 4; ++p) {
                const int nl = (t >> 5) + 8 * p;
                const float4* hr4 = (const float4*)&sH32[nl * 64];
                float acc = rb1b;
                #pragma unroll
                for (int qq = 0; qq < 16; ++qq) {
                    float4 hv = hr4[qq];
                    acc = fmaf(hv.x, colB[4 * qq + 0], acc);
                    acc = fmaf(hv.y, colB[4 * qq + 1], acc);
                    acc = fmaf(hv.z, colB[4 * qq + 2], acc);
                    acc = fmaf(hv.w, colB[4 * qq + 3], acc);
                }
                sX1[(rb + nl) * 32 + dL] = acc * sAny[rb + nl];
            }
        } else {
            #pragma unroll
            for (int p = 0; p < 4; ++p)
                sX1[(rb + (t >> 5) + 8 * p) * 32 + dL] = 0.f;
        }
        __syncthreads();                               // G_c
    }

    // ---- A2 = xn_j @ W2a (tile rows, [k][j] padded 18), W2a col in regs ----
    float colC[32];
    #pragma unroll
    for (int d = 0; d < 32; ++d) colC[d] = W2a[d * 64 + k];
    #pragma unroll
    for (int q = 0; q < 4; ++q) {
        const int jl = w + 4 * q;
        const float4* xr4 = (const float4*)&sXn[(jt * 16 + jl) * 32];
        float acc = 0.f;
        #pragma unroll
        for (int dq = 0; dq < 8; ++dq) {
            float4 xv = xr4[dq];
            acc = fmaf(xv.x, colC[4 * dq + 0], acc);
            acc = fmaf(xv.y, colC[4 * dq + 1], acc);
            acc = fmaf(xv.z, colC[4 * dq + 2], acc);
            acc = fmaf(xv.w, colC[4 * dq + 3], acc);
        }
        sA2[k * 18 + jl] = acc;
    }
    __syncthreads();                                   // H (xn dead after this)

    // ---- A1 = x1 @ W2a + b2a (rows < ICAP; overwrites xn/H region) ----
    const int ICAP = (iN + 3) & ~3;
    for (int n = w; n < ICAP; n += 4) {
        const float4* x14 = (const float4*)&sX1[n * 32];
        float acc = rb2a;
        #pragma unroll
        for (int dq = 0; dq < 8; ++dq) {
            float4 xv = x14[dq];
            acc = fmaf(xv.x, colC[4 * dq + 0], acc);
            acc = fmaf(xv.y, colC[4 * dq + 1], acc);
            acc = fmaf(xv.z, colC[4 * dq + 2], acc);
            acc = fmaf(xv.w, colC[4 * dq + 3], acc);
        }
        sA1[n * 65 + k] = acc;
    }
    __syncthreads();                                   // I

    // ---- S-phase: S[i][j] = c3 + sum_k gelu(A1[i][k]-A2[k][j]) * v2[k] ----
    const float c3 = sC3[0];
    {
        const int jp = t & 7;          // j-pair: columns 2jp, 2jp+1
        const int ic = t >> 3;         // i-chain: rows 4ic..4ic+3
        const int i0 = ic * 4;
        if (i0 < iN) {
            float a0x = c3, a0y = c3, a1x = c3, a1y = c3;
            float a2x = c3, a2y = c3, a3x = c3, a3y = c3;
            #pragma unroll 4
            for (int kk = 0; kk < 64; ++kk) {
                const float2 a2v = *(const float2*)&sA2[kk * 18 + 2 * jp];
                const float vk  = sV2[kk];
                const float* a1p = &sA1[i0 * 65 + kk];
                const float b0 = a1p[0];
                const float b1 = a1p[65];
                const float b2 = a1p[130];
                const float b3r = a1p[195];
                a0x = fmaf(gelu_f(b0 - a2v.x), vk, a0x);
                a0y = fmaf(gelu_f(b0 - a2v.y), vk, a0y);
                a1x = fmaf(gelu_f(b1 - a2v.x), vk, a1x);
                a1y = fmaf(gelu_f(b1 - a2v.y), vk, a1y);
                a2x = fmaf(gelu_f(b2 - a2v.x), vk, a2x);
                a2y = fmaf(gelu_f(b2 - a2v.y), vk, a2y);
                a3x = fmaf(gelu_f(b3r - a2v.x), vk, a3x);
                a3y = fmaf(gelu_f(b3r - a2v.y), vk, a3y);
            }
            *(float2*)&sS[(i0 + 0) * 18 + 2 * jp] = make_float2(a0x, a0y);
            *(float2*)&sS[(i0 + 1) * 18 + 2 * jp] = make_float2(a1x, a1y);
            *(float2*)&sS[(i0 + 2) * 18 + 2 * jp] = make_float2(a2x, a2y);
            *(float2*)&sS[(i0 + 3) * 18 + 2 * jp] = make_float2(a3x, a3y);
        }
    }
    __syncthreads();                                   // J

    // ---- aggregate + b3 + residual, mask, write out ----
    {
        const int j  = t >> 4;
        const int d0 = (t & 15) * 2;
        const int jg = jt * 16 + j;
        float s0 = 0.f, s1 = 0.f;
        #pragma unroll 4
        for (int i = 0; i < ICAP; ++i) {
            const float Sv = sS[i * 18 + j];
            const float2 xv = *(const float2*)&sX1[i * 32 + d0];
            s0 = fmaf(Sv, xv.x, s0);
            s1 = fmaf(Sv, xv.y, s1);
        }
        const float msk = sAny[jg];
        const float b3v = b3[0];
        const size_t ob = (size_t)bm * ND + jg * 32 + d0;
        const float2 xo = *(const float2*)&x[ob];
        float2 o;
        o.x = (s0 + b3v + xo.x) * msk;
        o.y = (s1 + b3v + xo.y) * msk;
        *(float2*)&out[ob] = o;
    }
}

extern "C" void kernel_launch(void* const* d_in, const int* in_sizes, int n_in,
                              void* d_out, int out_size, void* d_ws, size_t ws_size,
                              hipStream_t stream) {
    (void)in_sizes; (void)n_in; (void)d_ws; (void)ws_size; (void)out_size;
    const float* x      = (const float*)d_in[0];
    const float* x_size = (const float*)d_in[1];
    const float* W1a    = (const float*)d_in[2];
    const float* b1a    = (const float*)d_in[3];
    const float* W1b    = (const float*)d_in[4];
    const float* b1b    = (const float*)d_in[5];
    const float* W2a    = (const float*)d_in[6];
    const float* b2a    = (const float*)d_in[7];
    const float* W2b    = (const float*)d_in[8];
    const float* b2b    = (const float*)d_in[9];
    const float* w3     = (const float*)d_in[10];
    const float* b3     = (const float*)d_in[11];
    float* out = (float*)d_out;

    fused2<<<dim3(256), dim3(256), 0, stream>>>(
        x, x_size, W1a, b1a, W1b, b1b, W2a, b2a, W2b, b2b, w3, b3, out);
}

// Round 4
// 99.423 us; speedup vs baseline: 2.5083x; 1.0750x over previous
//
#include <hip/hip_runtime.h>

// B=4, M=8, N=128, D=32, K=2D=H=64
#define NNC 128
#define DDC 32
#define KKC 64
constexpr int ND = NNC * DDC;   // 4096 floats per (b,m)
#define SMALLV 1e-8f

__device__ __forceinline__ float gelu_f(float v) {
    // tanh-gelu folded: gelu(v) = v - v * rcp(1 + exp2(v*(a*v^2+b)))
    float v2 = v * v;
    float p  = fmaf(0.1029432f, v2, 2.3022082f);
    float e  = __builtin_amdgcn_exp2f(v * p);
    float r  = __builtin_amdgcn_rcpf(e + 1.0f);
    return fmaf(-v, r, v);
}

// ===========================================================================
// ONE ordinary kernel. Grid = 256 blocks = bm(32) x jt(8 tiles of 16 j),
// 512 threads/block (8 waves -> 2 waves/SIMD for latency hiding; round-3's
// 256-thread version ran at 1 wave/SIMD, fully latency-exposed).
//
// LDS arena: 16384 floats (64 KB), lifetime-overlaid (floats):
//   0      sX1   [128][32]  4096
//   4096   sA1   [128][68]  8704   (272-B rows, 16B-aligned for b128)
//            overlays (dead before sA1 written): sXn @4096 [128][32],
//            sH32 @8192 [32][64]
//   12800  sA2t  [16][68]   1088   ([j][k] row-major -> b128 along k)
//            overlay (dead before sA2t written): scr @12800 [512]
//   13888  sSt   [16][132]  2112   ([j][i] -> b128 along i in aggregation)
//   16000  sV2[64], 16064 sAny[128], 16192 sRed[8], 16200 sC3[1]
// Weight columns register-cached: colA=W1a[:,k], colB=W1b[:,dL], colC=W2a[:,k].
// S-phase reads all operands as ds_read_b128 (A1 row, A2t row, v2).
// ===========================================================================
__global__ __launch_bounds__(512, 1) void fused3(
    const float* __restrict__ x, const float* __restrict__ x_size,
    const float* __restrict__ W1a, const float* __restrict__ b1a,
    const float* __restrict__ W1b, const float* __restrict__ b1b,
    const float* __restrict__ W2a, const float* __restrict__ b2a,
    const float* __restrict__ W2b, const float* __restrict__ b2b,
    const float* __restrict__ w3, const float* __restrict__ b3,
    float* __restrict__ out)
{
    __shared__ __align__(16) float smem[16384];

    const int t   = threadIdx.x;
    const int blk = blockIdx.x;
    const int bm  = blk >> 3;
    const int jt  = blk & 7;
    const int k   = t & 63;
    const int w   = t >> 6;        // wave id 0..7
    const int dL  = t & 31;

    const int iN = (int)(x_size[bm >> 3] + 0.5f);

    float* sX1  = smem;
    float* sA1  = smem + 4096;
    float* sXn  = smem + 4096;     // overlay: dead before sA1 writes
    float* sH32 = smem + 8192;     // overlay: dead before sA1 writes
    float* scr  = smem + 12800;    // v2 partial scratch (early)
    float* sA2t = smem + 12800;    // [16][68], written after scr is dead
    float* sSt  = smem + 13888;    // [16][132]
    float* sV2  = smem + 16000;
    float* sAny = smem + 16064;
    float* sRed = smem + 16192;
    float* sC3  = smem + 16200;

    // ---- fully-invalid j-tile: write zeros, done (block-uniform) ----
    if (jt * 16 >= iN) {
        out[(size_t)bm * ND + jt * 512 + t] = 0.f;
        return;
    }

    // ---- stage: register-cache weight columns; v2/c3 partials; init ----
    float colA[32];                       // W1a[:, k]
    #pragma unroll
    for (int d = 0; d < 32; ++d) colA[d] = W1a[d * 64 + k];
    float colB[64];                       // W1b[:, dL]
    #pragma unroll
    for (int q = 0; q < 64; ++q) colB[q] = W1b[q * 32 + dL];
    const float rb1a = b1a[k];
    const float rb1b = b1b[dL];
    const float rb2a = b2a[k];

    {   // v2 partials: v2[kk] = sum_h W2b[kk][h]*w3[h]; 8-way split
        const int kk = t >> 3, hq = t & 7;
        float p = 0.f;
        #pragma unroll
        for (int h = 0; h < 8; ++h)
            p = fmaf(W2b[kk * 64 + hq * 8 + h], w3[hq * 8 + h], p);
        scr[t] = p;
    }
    if (t < 64) {                         // c3 = sum_h b2b[h]*w3[h]
        float q = b2b[t] * w3[t];
        #pragma unroll
        for (int off = 32; off; off >>= 1) q += __shfl_xor(q, off);
        if (t == 0) sC3[0] = q;
    }
    if (t < 128) sAny[t] = 0.f;
    __syncthreads();                                   // A

    // ---- stats over x[bm] (x held in regs v4) ----
    const float4* xs4 = (const float4*)(x + (size_t)bm * ND);
    float4 v4[2];
    float lsum = 0.f;
    #pragma unroll
    for (int s = 0; s < 2; ++s) {
        int f = t + s * 512;
        float4 q = xs4[f];
        v4[s] = q;
        lsum += q.x + q.y + q.z + q.w;
        if (q.x != 0.f || q.y != 0.f || q.z != 0.f || q.w != 0.f) sAny[f >> 3] = 1.f;
    }
    #pragma unroll
    for (int off = 32; off; off >>= 1) lsum += __shfl_xor(lsum, off);
    if ((t & 63) == 0) sRed[w] = lsum;
    __syncthreads();                                   // B
    if (t < 64) {                                      // finalize v2
        float vp = 0.f;
        #pragma unroll
        for (int q = 0; q < 8; ++q) vp += scr[t * 8 + q];
        sV2[t] = vp;
    }
    const float denom = x_size[bm >> 3] * 32.f;
    float mean = 0.f;
    #pragma unroll
    for (int r = 0; r < 8; ++r) mean += sRed[r];
    mean /= denom;

    float lsq = 0.f;
    #pragma unroll
    for (int s = 0; s < 2; ++s) {
        int f = t + s * 512;
        float mk = sAny[f >> 3];
        float dx = v4[s].x - mean, dy = v4[s].y - mean;
        float dz = v4[s].z - mean, dw = v4[s].w - mean;
        lsq += mk * (dx * dx + dy * dy + dz * dz + dw * dw);
    }
    #pragma unroll
    for (int off = 32; off; off >>= 1) lsq += __shfl_xor(lsq, off);
    __syncthreads();                                   // C (sRed WAR)
    if ((t & 63) == 0) sRed[w] = lsq;
    __syncthreads();                                   // D
    float sq = 0.f;
    #pragma unroll
    for (int r = 0; r < 8; ++r) sq += sRed[r];
    const float inv = 1.f / (sqrtf(sq / denom) + SMALLV);

    // ---- normalize -> sXn ----
    #pragma unroll
    for (int s = 0; s < 2; ++s) {
        int f = t + s * 512;
        float mk = sAny[f >> 3] * inv;
        float4 q = v4[s];
        q.x = (q.x - mean) * mk; q.y = (q.y - mean) * mk;
        q.z = (q.z - mean) * mk; q.w = (q.w - mean) * mk;
        ((float4*)sXn)[f] = q;
    }
    __syncthreads();                                   // E

    // ---- MLP1 in 32-row chunks ----
    for (int c = 0; c < 4; ++c) {
        const int rb = c * 32;
        const bool live = (rb < iN);
        if (live) {
            // H = gelu(xn@W1a + b1a): rows w + 8r, r<4
            #pragma unroll
            for (int r = 0; r < 4; ++r) {
                const int nl = w + 8 * r;
                const float4* xr4 = (const float4*)&sXn[(rb + nl) * 32];
                float acc = rb1a;
                #pragma unroll
                for (int dq = 0; dq < 8; ++dq) {
                    float4 xv = xr4[dq];
                    acc = fmaf(xv.x, colA[4 * dq + 0], acc);
                    acc = fmaf(xv.y, colA[4 * dq + 1], acc);
                    acc = fmaf(xv.z, colA[4 * dq + 2], acc);
                    acc = fmaf(xv.w, colA[4 * dq + 3], acc);
                }
                sH32[nl * 64 + k] = gelu_f(acc);
            }
        }
        __syncthreads();                               // F_c
        if (live) {
            // x1 = (H@W1b + b1b)*mask: rows (t>>5) + 16p, p<2
            #pragma unroll
            for (int p = 0; p < 2; ++p) {
                const int nl = (t >> 5) + 16 * p;
                const float4* hr4 = (const float4*)&sH32[nl * 64];
                float acc = rb1b;
                #pragma unroll
                for (int qq = 0; qq < 16; ++qq) {
                    float4 hv = hr4[qq];
                    acc = fmaf(hv.x, colB[4 * qq + 0], acc);
                    acc = fmaf(hv.y, colB[4 * qq + 1], acc);
                    acc = fmaf(hv.z, colB[4 * qq + 2], acc);
                    acc = fmaf(hv.w, colB[4 * qq + 3], acc);
                }
                sX1[(rb + nl) * 32 + dL] = acc * sAny[rb + nl];
            }
        } else {
            #pragma unroll
            for (int p = 0; p < 2; ++p)
                sX1[(rb + (t >> 5) + 16 * p) * 32 + dL] = 0.f;
        }
        __syncthreads();                               // G_c
    }

    // ---- A2t[j][k] = xn_j @ W2a (j rows of this tile), W2a col in regs ----
    float colC[32];
    #pragma unroll
    for (int d = 0; d < 32; ++d) colC[d] = W2a[d * 64 + k];
    #pragma unroll
    for (int q = 0; q < 2; ++q) {
        const int jl = w + 8 * q;
        const float4* xr4 = (const float4*)&sXn[(jt * 16 + jl) * 32];
        float acc = 0.f;
        #pragma unroll
        for (int dq = 0; dq < 8; ++dq) {
            float4 xv = xr4[dq];
            acc = fmaf(xv.x, colC[4 * dq + 0], acc);
            acc = fmaf(xv.y, colC[4 * dq + 1], acc);
            acc = fmaf(xv.z, colC[4 * dq + 2], acc);
            acc = fmaf(xv.w, colC[4 * dq + 3], acc);
        }
        sA2t[jl * 68 + k] = acc;
    }
    __syncthreads();                                   // H (xn/H32 dead now)

    // ---- A1 = x1 @ W2a + b2a (overwrites xn/H region) ----
    const int ICAP = (iN + 3) & ~3;
    for (int n = w; n < ICAP; n += 8) {
        const float4* x14 = (const float4*)&sX1[n * 32];
        float acc = rb2a;
        #pragma unroll
        for (int dq = 0; dq < 8; ++dq) {
            float4 xv = x14[dq];
            acc = fmaf(xv.x, colC[4 * dq + 0], acc);
            acc = fmaf(xv.y, colC[4 * dq + 1], acc);
            acc = fmaf(xv.z, colC[4 * dq + 2], acc);
            acc = fmaf(xv.w, colC[4 * dq + 3], acc);
        }
        sA1[n * 68 + k] = acc;
    }
    __syncthreads();                                   // I

    // ---- S-phase: thread = (j = t&15, i0 = 4*(t>>4)); all-b128 operands ----
    {
        const float c3 = sC3[0];
        const int j  = t & 15;
        const int i0 = (t >> 4) * 4;
        if (i0 < iN) {
            float a0 = c3, a1 = c3, a2 = c3, a3 = c3;
            const float* a2row = &sA2t[j * 68];
            const float* b0r = &sA1[(i0 + 0) * 68];
            const float* b1r = &sA1[(i0 + 1) * 68];
            const float* b2r = &sA1[(i0 + 2) * 68];
            const float* b3r = &sA1[(i0 + 3) * 68];
            #pragma unroll 4
            for (int kk = 0; kk < 64; kk += 4) {
                float4 va = *(const float4*)&a2row[kk];
                float4 vv = *(const float4*)&sV2[kk];
                float4 q0 = *(const float4*)&b0r[kk];
                float4 q1 = *(const float4*)&b1r[kk];
                float4 q2 = *(const float4*)&b2r[kk];
                float4 q3 = *(const float4*)&b3r[kk];
                a0 = fmaf(gelu_f(q0.x - va.x), vv.x, a0);
                a1 = fmaf(gelu_f(q1.x - va.x), vv.x, a1);
                a2 = fmaf(gelu_f(q2.x - va.x), vv.x, a2);
                a3 = fmaf(gelu_f(q3.x - va.x), vv.x, a3);
                a0 = fmaf(gelu_f(q0.y - va.y), vv.y, a0);
                a1 = fmaf(gelu_f(q1.y - va.y), vv.y, a1);
                a2 = fmaf(gelu_f(q2.y - va.y), vv.y, a2);
                a3 = fmaf(gelu_f(q3.y - va.y), vv.y, a3);
                a0 = fmaf(gelu_f(q0.z - va.z), vv.z, a0);
                a1 = fmaf(gelu_f(q1.z - va.z), vv.z, a1);
                a2 = fmaf(gelu_f(q2.z - va.z), vv.z, a2);
                a3 = fmaf(gelu_f(q3.z - va.z), vv.z, a3);
                a0 = fmaf(gelu_f(q0.w - va.w), vv.w, a0);
                a1 = fmaf(gelu_f(q1.w - va.w), vv.w, a1);
                a2 = fmaf(gelu_f(q2.w - va.w), vv.w, a2);
                a3 = fmaf(gelu_f(q3.w - va.w), vv.w, a3);
            }
            *(float4*)&sSt[j * 132 + i0] = make_float4(a0, a1, a2, a3);
        }
    }
    __syncthreads();                                   // J

    // ---- aggregate + b3 + residual, mask, write out (1 output/thread) ----
    {
        const int jA = t >> 5;         // 0..15
        const int dA = t & 31;
        const float* strow = &sSt[jA * 132];
        float s0 = 0.f;
        for (int i = 0; i < ICAP; i += 4) {
            float4 sv = *(const float4*)&strow[i];
            s0 = fmaf(sv.x, sX1[(i + 0) * 32 + dA], s0);
            s0 = fmaf(sv.y, sX1[(i + 1) * 32 + dA], s0);
            s0 = fmaf(sv.z, sX1[(i + 2) * 32 + dA], s0);
            s0 = fmaf(sv.w, sX1[(i + 3) * 32 + dA], s0);
        }
        const int jg = jt * 16 + jA;
        const float msk = sAny[jg];
        const size_t ob = (size_t)bm * ND + jg * 32 + dA;
        out[ob] = (s0 + b3[0] + x[ob]) * msk;
    }
}

extern "C" void kernel_launch(void* const* d_in, const int* in_sizes, int n_in,
                              void* d_out, int out_size, void* d_ws, size_t ws_size,
                              hipStream_t stream) {
    (void)in_sizes; (void)n_in; (void)d_ws; (void)ws_size; (void)out_size;
    const float* x      = (const float*)d_in[0];
    const float* x_size = (const float*)d_in[1];
    const float* W1a    = (const float*)d_in[2];
    const float* b1a    = (const float*)d_in[3];
    const float* W1b    = (const float*)d_in[4];
    const float* b1b    = (const float*)d_in[5];
    const float* W2a    = (const float*)d_in[6];
    const float* b2a    = (const float*)d_in[7];
    const float* W2b    = (const float*)d_in[8];
    const float* b2b    = (const float*)d_in[9];
    const float* w3     = (const float*)d_in[10];
    const float* b3     = (const float*)d_in[11];
    float* out = (float*)d_out;

    fused3<<<dim3(256), dim3(512), 0, stream>>>(
        x, x_size, W1a, b1a, W1b, b1b, W2a, b2a, W2b, b2b, w3, b3, out);
}